// Round 8
// baseline (1210.063 us; speedup 1.0000x reference)
//
#include <hip/hip_runtime.h>
#include <math.h>

#define HEADS 4
#define HID 610
#define HIDP 640   // K-padded row stride for MFMA (mult of 32)
#define FIN 128
#define KER 50
#define NOUT 86
#define NEG_SLOPE 0.2f

typedef short bf8_t __attribute__((ext_vector_type(8)));  // 8 bf16 (4 VGPRs)
typedef float f4_t __attribute__((ext_vector_type(4)));   // MFMA C/D

__device__ __forceinline__ ushort f2bf(float f) {  // RNE fp32->bf16
    unsigned u = __float_as_uint(f);
    unsigned r = (u + 0x7FFFu + ((u >> 16) & 1u)) >> 16;
    return (ushort)r;
}
__device__ __forceinline__ float bf2f(ushort b) { return __uint_as_float(((unsigned)b) << 16); }

// ---------------- utility ----------------
__global__ void fill_val(float* __restrict__ p, float v, long n) {
    long i = (long)blockIdx.x * blockDim.x + threadIdx.x;
    if (i < n) p[i] = v;
}

__global__ void copy_int(const int* __restrict__ a, int* __restrict__ b, int n) {
    int i = blockIdx.x * blockDim.x + threadIdx.x;
    if (i < n) b[i] = a[i];
}

// ---------------- edge sort by dst: histogram / scan / scatter ----------------
__global__ void hist_k(const int* __restrict__ ei, int* __restrict__ hist, int E) {
    int e = blockIdx.x * blockDim.x + threadIdx.x;
    if (e < E) atomicAdd(&hist[ei[E + e]], 1);
}

__global__ __launch_bounds__(1024) void scan_k(const int* __restrict__ hist,
                                               int* __restrict__ base, int Nn) {
    __shared__ int tmp[1024];
    __shared__ int carry;
    if (threadIdx.x == 0) carry = 0;
    __syncthreads();
    for (int c0 = 0; c0 < Nn; c0 += 1024) {
        int i = c0 + threadIdx.x;
        int v = (i < Nn) ? hist[i] : 0;
        tmp[threadIdx.x] = v;
        __syncthreads();
        for (int off = 1; off < 1024; off <<= 1) {
            int t = (threadIdx.x >= off) ? tmp[threadIdx.x - off] : 0;
            __syncthreads();
            tmp[threadIdx.x] += t;
            __syncthreads();
        }
        if (i < Nn) base[i] = carry + tmp[threadIdx.x] - v;  // exclusive
        __syncthreads();
        if (threadIdx.x == 1023) carry += tmp[1023];
        __syncthreads();
    }
    if (threadIdx.x == 0) base[Nn] = carry;
}

__global__ void scatter_k(const int* __restrict__ ei, int* __restrict__ cursor,
                          int* __restrict__ esrc, int E) {
    int e = blockIdx.x * blockDim.x + threadIdx.x;
    if (e >= E) return;
    int d = ei[E + e];
    int pos = atomicAdd(&cursor[d], 1);
    esrc[pos] = ei[e];
}

// ---------------- split fp32 -> bf16 hi/lo with K padding ----------------
__global__ void split_pad(const float* __restrict__ in, ushort* __restrict__ hi,
                          ushort* __restrict__ lo, int R, int K, int Kp) {
    long i = (long)blockIdx.x * blockDim.x + threadIdx.x;
    if (i >= (long)R * Kp) return;
    int r = (int)(i / Kp), c = (int)(i % Kp);
    float v = (c < K) ? in[(long)r * K + c] : 0.f;
    ushort h = f2bf(v);
    hi[i] = h;
    lo[i] = f2bf(v - bf2f(h));
}

// ---------------- U precompute: U[k,c] = sum_d w[(h*HID+d)*K + k] * att[h,d] ----------
// c = head + 4*(0:src,1:dst)  ->  c<4: att_src head c; c>=4: att_dst head c-4.
__global__ void compute_u(const float* __restrict__ w, const float* __restrict__ att_s,
                          const float* __restrict__ att_d, float* __restrict__ U,
                          int K, int Kp) {
    int gid = blockIdx.x * blockDim.x + threadIdx.x;
    if (gid >= Kp * 8) return;
    int k = gid % Kp, c = gid / Kp;
    int h = c & 3;
    const float* att = (c < 4) ? att_s : att_d;
    float acc = 0.f;
    if (k < K) {
        for (int d = 0; d < HID; d++)
            acc += w[((size_t)(h * HID + d)) * K + k] * att[h * HID + d];
    }
    U[k * 8 + c] = acc;
}

// ---------------- split-bf16 MFMA GEMM (unchanged from R7) ----------------
template <int AMODE, bool BIAS>
__global__ __launch_bounds__(256) void gemm_mfma(const float* __restrict__ A,
                                                 const ushort* __restrict__ Aghi,
                                                 const ushort* __restrict__ Aglo,
                                                 const ushort* __restrict__ Bghi,
                                                 const ushort* __restrict__ Bglo,
                                                 const float* __restrict__ bias,
                                                 float* __restrict__ C,
                                                 int M, int N, int Kp) {
    __shared__ __align__(16) ushort Ah[128 * 32];
    __shared__ __align__(16) ushort Al[128 * 32];
    __shared__ __align__(16) ushort Bh[128 * 32];
    __shared__ __align__(16) ushort Bl[128 * 32];
    int tid = threadIdx.x;
    int wave = tid >> 6, lane = tid & 63;
    int quad = lane >> 4, l16 = lane & 15;
    int wm = wave & 1, wn = wave >> 1;
    int row0 = blockIdx.y * 128, col0 = blockIdx.x * 128;

    float4 pa0[4];
    uint4 pah[2], pal[2], pbh[2], pbl[2];

    auto loadA = [&](int k0) {
        if (AMODE == 0) {
#pragma unroll
            for (int q = 0; q < 4; q++) {
                int p = tid + q * 256;
                int r = p >> 3, c4 = (p & 7) << 2;
                int gr = row0 + r;
                pa0[q] = (gr < M) ? *(const float4*)(A + (size_t)gr * Kp + k0 + c4)
                                  : make_float4(0.f, 0.f, 0.f, 0.f);
            }
        } else {
#pragma unroll
            for (int q = 0; q < 2; q++) {
                int p = tid + q * 256;
                int r = p >> 2, c = p & 3;
                int gr = row0 + r;
                if (gr < M) {
                    pah[q] = *(const uint4*)(Aghi + (size_t)gr * Kp + k0 + c * 8);
                    pal[q] = *(const uint4*)(Aglo + (size_t)gr * Kp + k0 + c * 8);
                } else {
                    pah[q] = make_uint4(0, 0, 0, 0);
                    pal[q] = make_uint4(0, 0, 0, 0);
                }
            }
        }
    };
    auto loadB = [&](int k0) {
#pragma unroll
        for (int q = 0; q < 2; q++) {
            int p = tid + q * 256;
            int r = p >> 2, c = p & 3;
            int gr = col0 + r;
            if (gr < N) {
                pbh[q] = *(const uint4*)(Bghi + (size_t)gr * Kp + k0 + c * 8);
                pbl[q] = *(const uint4*)(Bglo + (size_t)gr * Kp + k0 + c * 8);
            } else {
                pbh[q] = make_uint4(0, 0, 0, 0);
                pbl[q] = make_uint4(0, 0, 0, 0);
            }
        }
    };
    auto writeLDS = [&]() {
        if (AMODE == 0) {
#pragma unroll
            for (int q = 0; q < 4; q++) {
                int p = tid + q * 256;
                int r = p >> 3, m = p & 7;
                int pos = r * 32 + ((((m >> 1)) ^ ((r >> 1) & 3)) << 3) + ((m & 1) << 2);
                float4 v = pa0[q];
                ushort4 hv, lv;
                hv.x = f2bf(v.x); lv.x = f2bf(v.x - bf2f(hv.x));
                hv.y = f2bf(v.y); lv.y = f2bf(v.y - bf2f(hv.y));
                hv.z = f2bf(v.z); lv.z = f2bf(v.z - bf2f(hv.z));
                hv.w = f2bf(v.w); lv.w = f2bf(v.w - bf2f(hv.w));
                *(ushort4*)&Ah[pos] = hv;
                *(ushort4*)&Al[pos] = lv;
            }
        } else {
#pragma unroll
            for (int q = 0; q < 2; q++) {
                int p = tid + q * 256;
                int r = p >> 2, c = p & 3;
                int pos = r * 32 + ((c ^ ((r >> 1) & 3)) << 3);
                *(uint4*)&Ah[pos] = pah[q];
                *(uint4*)&Al[pos] = pal[q];
            }
        }
#pragma unroll
        for (int q = 0; q < 2; q++) {
            int p = tid + q * 256;
            int r = p >> 2, c = p & 3;
            int pos = r * 32 + ((c ^ ((r >> 1) & 3)) << 3);
            *(uint4*)&Bh[pos] = pbh[q];
            *(uint4*)&Bl[pos] = pbl[q];
        }
    };

    f4_t acc[4][4];
#pragma unroll
    for (int i = 0; i < 4; i++)
#pragma unroll
        for (int j = 0; j < 4; j++) acc[i][j] = (f4_t){0.f, 0.f, 0.f, 0.f};

    loadA(0);
    loadB(0);
    int sw = (quad ^ ((l16 >> 1) & 3)) << 3;
    for (int k0 = 0; k0 < Kp; k0 += 32) {
        __syncthreads();
        writeLDS();
        __syncthreads();
        if (k0 + 32 < Kp) {
            loadA(k0 + 32);
            loadB(k0 + 32);
        }
        bf8_t ah[4], al[4], bh[4], bl[4];
#pragma unroll
        for (int t = 0; t < 4; t++) {
            int ar = wm * 64 + t * 16 + l16;
            ah[t] = *(const bf8_t*)&Ah[ar * 32 + sw];
            al[t] = *(const bf8_t*)&Al[ar * 32 + sw];
            int br = wn * 64 + t * 16 + l16;
            bh[t] = *(const bf8_t*)&Bh[br * 32 + sw];
            bl[t] = *(const bf8_t*)&Bl[br * 32 + sw];
        }
#pragma unroll
        for (int i = 0; i < 4; i++)
#pragma unroll
            for (int j = 0; j < 4; j++) {
                acc[i][j] = __builtin_amdgcn_mfma_f32_16x16x32_bf16(ah[i], bh[j], acc[i][j], 0, 0, 0);
                acc[i][j] = __builtin_amdgcn_mfma_f32_16x16x32_bf16(al[i], bh[j], acc[i][j], 0, 0, 0);
                acc[i][j] = __builtin_amdgcn_mfma_f32_16x16x32_bf16(ah[i], bl[j], acc[i][j], 0, 0, 0);
            }
    }
#pragma unroll
    for (int i = 0; i < 4; i++) {
#pragma unroll
        for (int r = 0; r < 4; r++) {
            int grow = row0 + wm * 64 + i * 16 + quad * 4 + r;
            if (grow >= M) continue;
#pragma unroll
            for (int j = 0; j < 4; j++) {
                int gcol = col0 + wn * 64 + j * 16 + l16;
                if (gcol >= N) continue;
                float v = acc[i][j][r];
                if (BIAS) v += bias[gcol];
                C[(size_t)grow * N + gcol] = v;
            }
        }
    }
}

// ---------------- attention GEMV (layer1, fp32 x): a[n,c] = sum_k x[n,k] U[k,c] --------
__global__ __launch_bounds__(256) void attn_gemv_f32(const float* __restrict__ x,
                                                     const float* __restrict__ Ug,
                                                     float* __restrict__ a_src,
                                                     float* __restrict__ a_dst, int Nn) {
    __shared__ float Us[FIN * 9];  // stride 9: conflict-free
    for (int idx = threadIdx.x; idx < FIN * 8; idx += 256) {
        int k = idx >> 3, c = idx & 7;
        Us[k * 9 + c] = Ug[idx];
    }
    __syncthreads();
    int wave = threadIdx.x >> 6, lane = threadIdx.x & 63;
    int n = blockIdx.x * 4 + wave;
    if (n >= Nn) return;
    float acc[8] = {};
#pragma unroll
    for (int t = 0; t < 2; t++) {
        int k = lane + 64 * t;
        float v = x[(size_t)n * FIN + k];
#pragma unroll
        for (int c = 0; c < 8; c++) acc[c] = fmaf(v, Us[k * 9 + c], acc[c]);
    }
#pragma unroll
    for (int off = 32; off > 0; off >>= 1)
#pragma unroll
        for (int c = 0; c < 8; c++) acc[c] += __shfl_xor(acc[c], off);
    if (lane == 0) {
#pragma unroll
        for (int hh = 0; hh < 4; hh++) {
            a_src[n * HEADS + hh] = acc[hh];
            a_dst[n * HEADS + hh] = acc[4 + hh];
        }
    }
}

// ---------------- attention GEMV (layer2, split-bf16 x1) ----------------
__global__ __launch_bounds__(256) void attn_gemv_bf(const ushort* __restrict__ xhi,
                                                    const ushort* __restrict__ xlo,
                                                    const float* __restrict__ Ug,
                                                    float* __restrict__ a_src,
                                                    float* __restrict__ a_dst, int Nn) {
    __shared__ float Us[HIDP * 9];
    for (int idx = threadIdx.x; idx < HIDP * 8; idx += 256) {
        int k = idx >> 3, c = idx & 7;
        Us[k * 9 + c] = Ug[idx];
    }
    __syncthreads();
    int wave = threadIdx.x >> 6, lane = threadIdx.x & 63;
    int n = blockIdx.x * 4 + wave;
    if (n >= Nn) return;
    const ushort* hp = xhi + (size_t)n * HIDP;
    const ushort* lp = xlo + (size_t)n * HIDP;
    float acc[8] = {};
#pragma unroll
    for (int t = 0; t < 10; t++) {
        int k = lane + 64 * t;
        float v = bf2f(hp[k]) + bf2f(lp[k]);
#pragma unroll
        for (int c = 0; c < 8; c++) acc[c] = fmaf(v, Us[k * 9 + c], acc[c]);
    }
#pragma unroll
    for (int off = 32; off > 0; off >>= 1)
#pragma unroll
        for (int c = 0; c < 8; c++) acc[c] += __shfl_xor(acc[c], off);
    if (lane == 0) {
#pragma unroll
        for (int hh = 0; hh < 4; hh++) {
            a_src[n * HEADS + hh] = acc[hh];
            a_dst[n * HEADS + hh] = acc[4 + hh];
        }
    }
}

// ---------------- per-dst-node softmax + aggregation (atomic-free, CSR) ----------------
// Pass C gathers h rows with float2 loads (head offsets 610 floats = 8B aligned).
template <int OUTMODE>
__global__ __launch_bounds__(256) void node_aggregate(
    const float* __restrict__ h, const float* __restrict__ asrc,
    const float* __restrict__ adst, const int* __restrict__ base,
    const int* __restrict__ esrc, const float* __restrict__ bias,
    float* __restrict__ xout, ushort* __restrict__ xhi, ushort* __restrict__ xlo,
    int Nn) {
    int wave = threadIdx.x >> 6, lane = threadIdx.x & 63;
    int n = blockIdx.x * 4 + wave;
    if (n >= Nn) return;
    int b0 = base[n], deg = base[n + 1] - b0;
    float ad[HEADS];
#pragma unroll
    for (int hh = 0; hh < HEADS; hh++) ad[hh] = adst[n * HEADS + hh];
    float m[HEADS] = {-INFINITY, -INFINITY, -INFINITY, -INFINITY};
    for (int eb = 0; eb < deg; eb += 64) {
        int i = eb + lane;
        if (i < deg) {
            int s = esrc[b0 + i];
#pragma unroll
            for (int hh = 0; hh < HEADS; hh++) {
                float v = asrc[s * HEADS + hh] + ad[hh];
                v = v >= 0.f ? v : NEG_SLOPE * v;
                m[hh] = fmaxf(m[hh], v);
            }
        }
    }
#pragma unroll
    for (int off = 32; off > 0; off >>= 1)
#pragma unroll
        for (int hh = 0; hh < HEADS; hh++) m[hh] = fmaxf(m[hh], __shfl_xor(m[hh], off));
    float sden[HEADS] = {0.f, 0.f, 0.f, 0.f};
    for (int eb = 0; eb < deg; eb += 64) {
        int i = eb + lane;
        if (i < deg) {
            int s = esrc[b0 + i];
#pragma unroll
            for (int hh = 0; hh < HEADS; hh++) {
                float v = asrc[s * HEADS + hh] + ad[hh];
                v = v >= 0.f ? v : NEG_SLOPE * v;
                sden[hh] += expf(v - m[hh]);
            }
        }
    }
#pragma unroll
    for (int off = 32; off > 0; off >>= 1)
#pragma unroll
        for (int hh = 0; hh < HEADS; hh++) sden[hh] += __shfl_xor(sden[hh], off);
    float inv[HEADS];
#pragma unroll
    for (int hh = 0; hh < HEADS; hh++) inv[hh] = 0.25f / (sden[hh] + 1e-16f);
    // pass C: float2 accumulators, 5 tiles of 64 float2 covering 305 pairs (=610 floats)
    float2 a0[5], a1[5], a2[5], a3[5];
#pragma unroll
    for (int t = 0; t < 5; t++) {
        a0[t] = make_float2(0.f, 0.f); a1[t] = make_float2(0.f, 0.f);
        a2[t] = make_float2(0.f, 0.f); a3[t] = make_float2(0.f, 0.f);
    }
    for (int eb = 0; eb < deg; eb += 64) {
        int i = eb + lane;
        int sreg = 0;
        float coef[HEADS] = {0.f, 0.f, 0.f, 0.f};
        if (i < deg) {
            sreg = esrc[b0 + i];
#pragma unroll
            for (int hh = 0; hh < HEADS; hh++) {
                float v = asrc[sreg * HEADS + hh] + ad[hh];
                v = v >= 0.f ? v : NEG_SLOPE * v;
                coef[hh] = expf(v - m[hh]) * inv[hh];
            }
        }
        int cnt = deg - eb < 64 ? deg - eb : 64;
        for (int j = 0; j < cnt; j++) {
            int s = __shfl(sreg, j);
            float c0 = __shfl(coef[0], j), c1 = __shfl(coef[1], j);
            float c2 = __shfl(coef[2], j), c3 = __shfl(coef[3], j);
            const float2* hr2 = (const float2*)(h + (size_t)s * (HEADS * HID));
#pragma unroll
            for (int t = 0; t < 5; t++) {
                int f = lane + t * 64;
                if (f < 305) {
                    float2 v0 = hr2[f];
                    float2 v1 = hr2[305 + f];
                    float2 v2 = hr2[610 + f];
                    float2 v3 = hr2[915 + f];
                    a0[t].x = fmaf(c0, v0.x, a0[t].x); a0[t].y = fmaf(c0, v0.y, a0[t].y);
                    a1[t].x = fmaf(c1, v1.x, a1[t].x); a1[t].y = fmaf(c1, v1.y, a1[t].y);
                    a2[t].x = fmaf(c2, v2.x, a2[t].x); a2[t].y = fmaf(c2, v2.y, a2[t].y);
                    a3[t].x = fmaf(c3, v3.x, a3[t].x); a3[t].y = fmaf(c3, v3.y, a3[t].y);
                }
            }
        }
    }
    const float2* b2p = (const float2*)bias;
#pragma unroll
    for (int t = 0; t < 5; t++) {
        int f = lane + t * 64;
        if (f < 305) {
            float2 bv = b2p[f];
            float vx = a0[t].x + a1[t].x + a2[t].x + a3[t].x + bv.x;
            float vy = a0[t].y + a1[t].y + a2[t].y + a3[t].y + bv.y;
            vx = vx > 0.f ? vx : 0.f;
            vy = vy > 0.f ? vy : 0.f;
            if (OUTMODE == 0) {
                *(float2*)&xout[(size_t)n * HIDP + 2 * f] = make_float2(vx, vy);
            } else {
                ushort2 hv, lv;
                hv.x = f2bf(vx); lv.x = f2bf(vx - bf2f(hv.x));
                hv.y = f2bf(vy); lv.y = f2bf(vy - bf2f(hv.y));
                *(ushort2*)&xhi[(size_t)n * HIDP + 2 * f] = hv;
                *(ushort2*)&xlo[(size_t)n * HIDP + 2 * f] = lv;
            }
        }
    }
    for (int d = HID + lane; d < HIDP; d += 64) {
        if (OUTMODE == 0) {
            xout[(size_t)n * HIDP + d] = 0.f;
        } else {
            xhi[(size_t)n * HIDP + d] = 0;
            xlo[(size_t)n * HIDP + d] = 0;
        }
    }
}

// ---------------- fused edge conv (unchanged from R7) ----------------
__device__ __forceinline__ int ystag(int j) { return j + (j >> 3); }

__global__ __launch_bounds__(256) void edge_conv(const float* __restrict__ x2,
                                                 const int* __restrict__ ei,
                                                 const float* __restrict__ w4,
                                                 const float* __restrict__ b4,
                                                 const float* __restrict__ w6,
                                                 const float* __restrict__ b6,
                                                 ushort* __restrict__ zhi,
                                                 ushort* __restrict__ zlo, int E) {
    __shared__ __align__(16) float2 st[4][632];
    __shared__ __align__(16) float y[4][652];
    int wave = threadIdx.x >> 6;
    int lane = threadIdx.x & 63;
    int e = blockIdx.x * 4 + wave;
    bool active = (e < E);
    if (active) {
        int sidx = ei[e];
        int didx = ei[E + e];
        const float2* sp = (const float2*)(x2 + (long)sidx * HIDP);
        const float2* tp = (const float2*)(x2 + (long)didx * HIDP);
        for (int i = lane; i < HID / 2; i += 64) {
            float2 sv = sp[i], tv = tp[i];
            *(float4*)&st[wave][2 * i] = make_float4(sv.x, tv.x, sv.y, tv.y);
        }
    }
    __syncthreads();
    float bb4 = b4[0], bb6 = b6[0];
    if (active) {
        int j0 = lane * 9;
        float acc[9];
        float2 W[18];
#pragma unroll
        for (int i = 0; i < 9; i++) acc[i] = bb4;
#pragma unroll
        for (int p = 0; p < 18; p++) W[p] = st[wave][j0 + p];
#pragma unroll
        for (int g = 0; g < 6; g++) {
#pragma unroll
            for (int mm = 0; mm < 9; mm++) {
                int k = 9 * g + mm;
                if (k < KER) {
                    float ws_ = w4[k], wt_ = w4[KER + k];
#pragma unroll
                    for (int i = 0; i < 9; i++) {
                        float2 v = W[(9 * g + mm + i) % 18];
                        acc[i] = fmaf(v.x, ws_, acc[i]);
                        acc[i] = fmaf(v.y, wt_, acc[i]);
                    }
                }
            }
            if (g < 5) {
#pragma unroll
                for (int p = 0; p < 9; p++)
                    W[(9 * g + p) % 18] = st[wave][j0 + 9 * g + 18 + p];
            }
        }
#pragma unroll
        for (int i = 0; i < 9; i++)
            y[wave][ystag(j0 + i)] = acc[i] > 0.f ? acc[i] : 0.f;
    }
    __syncthreads();
    if (active) {
        int j0 = lane * 8;
        float acc[8];
        float Y[16];
#pragma unroll
        for (int i = 0; i < 8; i++) acc[i] = bb6;
#pragma unroll
        for (int p = 0; p < 16; p++) Y[p] = y[wave][ystag(j0 + p)];
#pragma unroll
        for (int g = 0; g < 7; g++) {
#pragma unroll
            for (int mm = 0; mm < 8; mm++) {
                int k = 8 * g + mm;
                if (k < KER) {
                    float wv = w6[k];
#pragma unroll
                    for (int i = 0; i < 8; i++)
                        acc[i] = fmaf(Y[(8 * g + mm + i) % 16], wv, acc[i]);
                }
            }
            if (g < 6) {
#pragma unroll
                for (int p = 0; p < 8; p++)
                    Y[(8 * g + p) % 16] = y[wave][ystag(j0 + 8 * g + 16 + p)];
            }
        }
        ushort4 zh0, zh1, zl0, zl1;
        float v;
        v = acc[0] > 0.f ? acc[0] : 0.f; zh0.x = f2bf(v); zl0.x = f2bf(v - bf2f(zh0.x));
        v = acc[1] > 0.f ? acc[1] : 0.f; zh0.y = f2bf(v); zl0.y = f2bf(v - bf2f(zh0.y));
        v = acc[2] > 0.f ? acc[2] : 0.f; zh0.z = f2bf(v); zl0.z = f2bf(v - bf2f(zh0.z));
        v = acc[3] > 0.f ? acc[3] : 0.f; zh0.w = f2bf(v); zl0.w = f2bf(v - bf2f(zh0.w));
        v = acc[4] > 0.f ? acc[4] : 0.f; zh1.x = f2bf(v); zl1.x = f2bf(v - bf2f(zh1.x));
        v = acc[5] > 0.f ? acc[5] : 0.f; zh1.y = f2bf(v); zl1.y = f2bf(v - bf2f(zh1.y));
        v = acc[6] > 0.f ? acc[6] : 0.f; zh1.z = f2bf(v); zl1.z = f2bf(v - bf2f(zh1.z));
        v = acc[7] > 0.f ? acc[7] : 0.f; zh1.w = f2bf(v); zl1.w = f2bf(v - bf2f(zh1.w));
        size_t zo = (size_t)e * 512 + j0;
        *(ushort4*)&zhi[zo] = zh0;
        *(ushort4*)&zhi[zo + 4] = zh1;
        *(ushort4*)&zlo[zo] = zl0;
        *(ushort4*)&zlo[zo + 4] = zl1;
    }
}

extern "C" void kernel_launch(void* const* d_in, const int* in_sizes, int n_in,
                              void* d_out, int out_size, void* d_ws, size_t ws_size,
                              hipStream_t stream) {
    const float* x = (const float*)d_in[0];
    const int* ei = (const int*)d_in[1];  // int32
    const float* w0 = (const float*)d_in[2];
    const float* b0 = (const float*)d_in[3];
    const float* att_s0 = (const float*)d_in[4];
    const float* att_d0 = (const float*)d_in[5];
    const float* w2 = (const float*)d_in[6];
    const float* b2 = (const float*)d_in[7];
    const float* att_s1 = (const float*)d_in[8];
    const float* att_d1 = (const float*)d_in[9];
    const float* w4 = (const float*)d_in[10];
    const float* b4 = (const float*)d_in[11];
    const float* w6 = (const float*)d_in[12];
    const float* b6 = (const float*)d_in[13];
    const float* w8 = (const float*)d_in[14];
    const float* b8 = (const float*)d_in[15];
    float* out = (float*)d_out;

    const int Nn = in_sizes[0] / FIN;  // 20000
    const int E = in_sizes[1] / 2;     // 100000
    const int HD = HEADS * HID;        // 2440

    // ---- workspace layout (floats), watermark same as proven-safe R5-R7 (~255 MB) ----
    float* ws = (float*)d_ws;
    size_t o = 0;
    float* buf1 = ws + o; o += (size_t)Nn * HIDP;  // layer1: x1 bf16 hi/lo; layer2: x2 fp32
    ushort* x1hi = (ushort*)buf1;
    ushort* x1lo = x1hi + (size_t)Nn * HIDP;
    ushort* w8hi = (ushort*)(ws + o);
    ushort* w8lo = w8hi + (size_t)NOUT * 512; o += (size_t)NOUT * 512;
    // z (bf16 hi/lo) overlays everything from here on
    ushort* zhi = (ushort*)(ws + o);
    ushort* zlo = zhi + (size_t)E * 512;
    int* base = (int*)(ws + o); o += (size_t)Nn + 4;
    int* cursor = (int*)(ws + o); o += (size_t)Nn;  // also hist
    int* esrc = (int*)(ws + o); o += (size_t)E;
    float* asrc = ws + o; o += (size_t)Nn * HEADS;
    float* adst = ws + o; o += (size_t)Nn * HEADS;
    float* U0 = ws + o; o += (size_t)FIN * 8;
    float* U2 = ws + o; o += (size_t)HIDP * 8;
    ushort* w0hi = (ushort*)(ws + o);
    ushort* w0lo = w0hi + (size_t)HD * FIN; o += (size_t)HD * FIN;
    ushort* w2hi = (ushort*)(ws + o);
    ushort* w2lo = w2hi + (size_t)HD * HIDP; o += (size_t)HD * HIDP;
    float* h = ws + o;  // Nn*2440 fp32

    int edgeGrid = (E + 255) / 256;
    int nodeWaveGrid = (Nn + 3) / 4;
    int edgeConvGrid = (E + 3) / 4;
    dim3 gGemmL((HD + 127) / 128, (Nn + 127) / 128);   // 20 x 157
    dim3 gGemmF((NOUT + 127) / 128, (E + 127) / 128);  // 1 x 782

    // ---- one-time: weight split + U precompute + edge sort by dst ----
    split_pad<<<((HD * FIN) + 255) / 256, 256, 0, stream>>>(w0, w0hi, w0lo, HD, FIN, FIN);
    split_pad<<<((HD * HIDP) + 255) / 256, 256, 0, stream>>>(w2, w2hi, w2lo, HD, HID, HIDP);
    split_pad<<<((NOUT * 512) + 255) / 256, 256, 0, stream>>>(w8, w8hi, w8lo, NOUT, 512, 512);
    compute_u<<<(FIN * 8 + 255) / 256, 256, 0, stream>>>(w0, att_s0, att_d0, U0, FIN, FIN);
    compute_u<<<(HIDP * 8 + 255) / 256, 256, 0, stream>>>(w2, att_s1, att_d1, U2, HID, HIDP);
    fill_val<<<(Nn + 255) / 256, 256, 0, stream>>>((float*)cursor, 0.f, Nn);  // hist=0
    hist_k<<<edgeGrid, 256, 0, stream>>>(ei, cursor, E);
    scan_k<<<1, 1024, 0, stream>>>(cursor, base, Nn);
    copy_int<<<(Nn + 255) / 256, 256, 0, stream>>>(base, cursor, Nn);
    scatter_k<<<edgeGrid, 256, 0, stream>>>(ei, cursor, esrc, E);

    // ---------- GAT layer 1 ----------
    gemm_mfma<0, false><<<gGemmL, 256, 0, stream>>>(x, nullptr, nullptr, w0hi, w0lo, nullptr,
                                                    h, Nn, HD, FIN);
    attn_gemv_f32<<<nodeWaveGrid, 256, 0, stream>>>(x, U0, asrc, adst, Nn);
    node_aggregate<1><<<nodeWaveGrid, 256, 0, stream>>>(h, asrc, adst, base, esrc, b0,
                                                        nullptr, x1hi, x1lo, Nn);

    // ---------- GAT layer 2 ----------
    gemm_mfma<1, false><<<gGemmL, 256, 0, stream>>>(nullptr, x1hi, x1lo, w2hi, w2lo, nullptr,
                                                    h, Nn, HD, HIDP);
    attn_gemv_bf<<<nodeWaveGrid, 256, 0, stream>>>(x1hi, x1lo, U2, asrc, adst, Nn);
    node_aggregate<0><<<nodeWaveGrid, 256, 0, stream>>>(h, asrc, adst, base, esrc, b2,
                                                        buf1, nullptr, nullptr, Nn);

    // ---------- edge conv -> z as bf16 hi/lo ----------
    edge_conv<<<edgeConvGrid, 256, 0, stream>>>(buf1, ei, w4, b4, w6, b6, zhi, zlo, E);

    // ---------- final linear: out = z @ w8^T + b8 ----------
    gemm_mfma<1, true><<<gGemmF, 256, 0, stream>>>(nullptr, zhi, zlo, w8hi, w8lo, b8,
                                                   out, E, NOUT, 512);
}